// Round 11
// baseline (131.133 us; speedup 1.0000x reference)
//
#include <hip/hip_runtime.h>
#include <hip/hip_bf16.h>

#define B_  1024
#define LA  529   // token positions -> conv channels
#define EE  100   // embedding dim -> conv steps
#define NF  16    // conv filters
#define NT  50    // conv output steps
#define NS  25    // pooled steps
#define NU  100   // LSTM units
#define NJ  400   // 4*NU

typedef float    f32x4v __attribute__((ext_vector_type(4)));
typedef short    s16x8  __attribute__((ext_vector_type(8)));
typedef _Float16 h2v    __attribute__((ext_vector_type(2)));
typedef _Float16 h16x8  __attribute__((ext_vector_type(8)));

__device__ __forceinline__ float leaky(float v) { return v >= 0.f ? v : 0.2f * v; }

__device__ __forceinline__ unsigned int pkh2(float x, float y) {
    auto p = __builtin_amdgcn_cvt_pkrtz(x, y);
    return __builtin_bit_cast(unsigned int, p);
}
__device__ __forceinline__ unsigned short f2h(float x) {
    return __builtin_bit_cast(unsigned short, (_Float16)x);
}
__device__ __forceinline__ float fdot2h(unsigned int e, unsigned int w, float acc) {
#if __has_builtin(__builtin_amdgcn_fdot2)
    return __builtin_amdgcn_fdot2(__builtin_bit_cast(h2v, e),
                                  __builtin_bit_cast(h2v, w), acc, false);
#else
    h2v ev = __builtin_bit_cast(h2v, e), wv = __builtin_bit_cast(h2v, w);
    return acc + (float)ev.x * (float)wv.x + (float)ev.y * (float)wv.y;
#endif
}

// ---------------- Kernel P: fp32 -> fp16 conversion ----------------
__global__ __launch_bounds__(256) void prep_kernel(
    const float* __restrict__ emb,      // [V*E]
    const float* __restrict__ conv_w,   // [2][529][16]
    unsigned int* __restrict__ emb_h,   // [V*E/2] packed half2
    unsigned int* __restrict__ convw_h) // [529*16] packed (w0,w1)
{
    const int gid = blockIdx.x * 256 + threadIdx.x;
    const int stride = gridDim.x * 256;
    for (int i = gid; i < (15245 * 100) / 2; i += stride) {
        const float2 v = ((const float2*)emb)[i];
        emb_h[i] = pkh2(v.x, v.y);
    }
    for (int i = gid; i < LA * NF; i += stride)
        convw_h[i] = pkh2(conv_w[i], conv_w[LA * NF + i]);
}

// ---------------- Kernel A: gather + conv + relu + maxpool ----------------
// 256 blocks x 512 threads, 4 batches/block. Wave w owns cols [67w, 67w+NC).
// Weights + tokens read straight from global with wave-uniform addresses
// (scalar-pipe candidates; zero LDS in the hot loop). Each weight column is
// fetched once per 4 batches (4x less than round 10). Partials merged via
// conflict-free ds atomics into t-major y.
__global__ __launch_bounds__(512, 2) void conv_embed_kernel(
    const int*          __restrict__ tokens,
    const unsigned int* __restrict__ emb_h,   // [V][50] half2 rows
    const unsigned int* __restrict__ convw_h, // [529][16] (w0,w1) half2
    const float*        __restrict__ conv_b,
    float*              __restrict__ p_out)   // [B][25][16]
{
    __shared__ float y[4][NF][52];   // t-major: atomics hit distinct banks

    const int tid  = threadIdx.x;
    const int lane = tid & 63;
    const int w    = __builtin_amdgcn_readfirstlane(tid >> 6);
    const int b0   = blockIdx.x * 4;
    const int t    = lane < NT ? lane : (NT - 1);

    for (int i = tid; i < 4 * NF * 52; i += 512) ((float*)y)[i] = 0.f;
    __syncthreads();

    const int c0 = w * 67;
    const int NC = (LA - c0) < 67 ? (LA - c0) : 67;   // w=7 -> 60
    const int* __restrict__ tokb = tokens + (size_t)b0 * LA;

    float acc[4][NF];
#pragma unroll
    for (int bb = 0; bb < 4; ++bb)
#pragma unroll
        for (int f = 0; f < NF; ++f) acc[bb][f] = 0.f;

#define LOADE(dst, i_) do { \
    const int ii = (i_); \
    const int cc = c0 + (ii < NC ? ii : (NC - 1)); \
    _Pragma("unroll") \
    for (int bb = 0; bb < 4; ++bb) { \
        const int tk = tokb[bb * LA + cc]; \
        unsigned int v = emb_h[(size_t)tk * 50 + t]; \
        if (ii >= NC) v = 0u; \
        dst[bb] = v; \
    } } while (0)

    unsigned int e0[4], e1[4];
    LOADE(e0, 0);
    LOADE(e1, 1);

    for (int i = 0; i < NC; ++i) {
        unsigned int en[4];
        LOADE(en, i + 2);
        const unsigned int* wp = convw_h + (size_t)(c0 + i) * NF;  // uniform addr
        unsigned int wv[NF];
#pragma unroll
        for (int q = 0; q < 4; ++q) ((uint4*)wv)[q] = ((const uint4*)wp)[q];
#pragma unroll
        for (int bb = 0; bb < 4; ++bb)
#pragma unroll
            for (int f = 0; f < NF; ++f)
                acc[bb][f] = fdot2h(e0[bb], wv[f], acc[bb][f]);
#pragma unroll
        for (int bb = 0; bb < 4; ++bb) { e0[bb] = e1[bb]; e1[bb] = en[bb]; }
    }
#undef LOADE

    if (lane < NT) {
#pragma unroll
        for (int bb = 0; bb < 4; ++bb)
#pragma unroll
            for (int f = 0; f < NF; ++f)
                atomicAdd(&y[bb][f][t], acc[bb][f]);   // bank = t: conflict-free
    }
    __syncthreads();

    // bias + relu + maxpool (relu(max(y0,y1)+b) == max(relu(y0+b),relu(y1+b)))
    for (int idx = tid; idx < 4 * NS * NF; idx += 512) {
        const int bb = idx / 400, r = idx - bb * 400;
        const int s = r >> 4, f = r & 15;
        const float m = fmaxf(y[bb][f][2 * s], y[bb][f][2 * s + 1]);
        p_out[(size_t)(b0 + bb) * (NS * NF) + r] = fmaxf(m + conv_b[f], 0.f);
    }
}

// ---------------- Kernel B: fp16 MFMA LSTM, wave-per-gate ----------------
// 512 blocks x 256 threads (4 waves), 2 batches/block -> 2 blocks/CU overlap.
// Wave g owns gate g: B-frags = 7 u-tiles x 4 chunks = 112 VGPR fp16
// (registers; fits well under the 256 cap at 2 waves/SIMD).
// Per step: 4 ds_read_b128 (A) + 28 MFMA + 7 z-writes, then a light gate
// phase on threads 0..199. Two barriers/step; LDS traffic ~20 instrs/step.
__global__ __launch_bounds__(256, 2) void lstm_mfma4_kernel(
    const float* __restrict__ p_in,    // [B][25][16]
    const float* __restrict__ k_lstm,  // [16][400]
    const float* __restrict__ rk,      // [100][400]
    const float* __restrict__ b_lstm,  // [400]
    const float* __restrict__ w1,      // [100][64]
    const float* __restrict__ b1,      // [64]
    const float* __restrict__ w2,      // [64][3]
    const float* __restrict__ b2,      // [3]
    float*       __restrict__ out)     // [B][3]
{
    __shared__ __align__(16) unsigned short a_lds[2][4][64][8]; // A dbuf, 8 KB
    __shared__ __align__(16) float z_lds[4][112][16];           // 28.7 KB
    __shared__ float hf[2][NU];
    __shared__ float db[2][64];
    __shared__ float lgl[2][4];

    const int tid  = threadIdx.x;
    const int lane = tid & 63;
    const int g    = __builtin_amdgcn_readfirstlane(tid >> 6);  // gate 0..3
    const int b0   = blockIdx.x * 2;
    const int colc = lane & 15;
    const int krow = lane >> 4;

    for (int i = tid; i < 2 * 4 * 64 * 8; i += 256) ((unsigned short*)a_lds)[i] = 0;

    // ---- B-frags in registers: gate g, 7 u-tiles (units padded to 112) ----
    h16x8 bf[7][4];
#pragma unroll
    for (int ut = 0; ut < 7; ++ut) {
        const int jl = ut * 16 + colc;              // unit 0..111
        const int jg = g * NU + (jl < NU ? jl : 0);
#pragma unroll
        for (int c = 0; c < 4; ++c) {
#pragma unroll
            for (int e = 0; e < 8; ++e) {
                const int k = c * 32 + krow * 8 + e;
                float x = 0.f;
                if (jl < NU) {
                    if (k < NU)        x = rk[k * NJ + jg];
                    else if (k < 116)  x = k_lstm[(k - NU) * NJ + jg];
                    else if (k == 116) x = b_lstm[jg];
                }
                bf[ut][c][e] = (_Float16)x;
            }
        }
    }
    __syncthreads();   // a_lds zeroing complete

    // p(t=0) rows 0..1 + bias slot (k=116, fp16 1.0) both buffers
    if (tid < 32) {
        const int pb = tid >> 4, pf = tid & 15;
        const float pv = p_in[(size_t)(b0 + pb) * (NS * NF) + pf];
        const int k = 100 + pf;
        a_lds[0][k >> 5][(((k >> 3) & 3) << 4) + pb][k & 7] = f2h(pv);
    }
    if (tid < 2) {
        a_lds[0][3][32 + tid][4] = 0x3C00;
        a_lds[1][3][32 + tid][4] = 0x3C00;
    }
    float cst = 0.f;
    const int gb = tid & 1, gu = tid >> 1;   // gate threads (tid < 200)
    __syncthreads();

#pragma unroll 1
    for (int t = 0; t < NS; ++t) {
        const int cur = t & 1, nxt = cur ^ 1;
        // prefetch p(t+1): 32 threads, hidden under phase A
        float pv = 0.f;
        if (tid >= 224 && t + 1 < NS) {
            const int pb = (tid - 224) >> 4, pf = tid & 15;
            pv = p_in[(size_t)(b0 + pb) * (NS * NF) + (t + 1) * NF + pf];
        }
        // ---- phase A: Z_g = A @ B_g (all 4 waves) ----
        h16x8 ah[4];
#pragma unroll
        for (int c = 0; c < 4; ++c)
            ah[c] = __builtin_bit_cast(h16x8, ((const s16x8*)a_lds[cur][c])[lane]);
#pragma unroll
        for (int ut = 0; ut < 7; ++ut) {
            f32x4v z = {0.f, 0.f, 0.f, 0.f};
#pragma unroll
            for (int c = 0; c < 4; ++c)
                z = __builtin_amdgcn_mfma_f32_16x16x32_f16(ah[c], bf[ut][c], z, 0, 0, 0);
            ((f32x4v*)&z_lds[g][ut * 16 + colc][0])[krow] = z;  // rows 2..15 unused
        }
        __syncthreads();
        // ---- phase B: gates on threads 0..199 (1 (u,b) pair each) ----
        if (tid < 2 * NU) {
            const float zi = z_lds[0][gu][gb];
            const float zf = z_lds[1][gu][gb];
            const float zg = z_lds[2][gu][gb];
            const float zo = z_lds[3][gu][gb];
            const float ig  = 1.f / (1.f + __expf(-zi));
            const float fg_ = 1.f / (1.f + __expf(-zf));
            const float og  = 1.f / (1.f + __expf(-zo));
            cst = fg_ * cst + ig * leaky(zg);
            const float h = og * leaky(cst);
            a_lds[nxt][gu >> 5][(((gu >> 3) & 3) << 4) + gb][gu & 7] = f2h(h);
            if (t == NS - 1) hf[gb][gu] = h;
        } else if (tid >= 224 && t + 1 < NS) {
            const int pb = (tid - 224) >> 4, pf = tid & 15;
            const int k = 100 + pf;
            a_lds[nxt][k >> 5][(((k >> 3) & 3) << 4) + pb][k & 7] = f2h(pv);
        }
        __syncthreads();
    }

    // dense head: d = tanh(h @ w1 + b1), 128 outputs
    if (tid < 128) {
        const int hb = tid >> 6, m = tid & 63;
        float a = b1[m];
#pragma unroll 4
        for (int u = 0; u < NU; ++u) a += hf[hb][u] * w1[u * 64 + m];
        db[hb][m] = tanhf(a);
    }
    __syncthreads();
    if (tid < 6) {
        const int bb = tid / 3, cls = tid - bb * 3;
        float l = b2[cls];
        for (int m = 0; m < 64; ++m) l += db[bb][m] * w2[m * 3 + cls];
        lgl[bb][cls] = l;
    }
    __syncthreads();
    if (tid < 2) {
        const float l0 = lgl[tid][0], l1 = lgl[tid][1], l2 = lgl[tid][2];
        const float mx = fmaxf(l0, fmaxf(l1, l2));
        const float e0 = __expf(l0 - mx), e1 = __expf(l1 - mx), e2 = __expf(l2 - mx);
        const float inv = 1.f / (e0 + e1 + e2);
        out[(b0 + tid) * 3 + 0] = e0 * inv;
        out[(b0 + tid) * 3 + 1] = e1 * inv;
        out[(b0 + tid) * 3 + 2] = e2 * inv;
    }
}

extern "C" void kernel_launch(void* const* d_in, const int* in_sizes, int n_in,
                              void* d_out, int out_size, void* d_ws, size_t ws_size,
                              hipStream_t stream) {
    const int*   tokens = (const int*)  d_in[0];
    const float* emb    = (const float*)d_in[1];
    const float* conv_w = (const float*)d_in[2];
    const float* conv_b = (const float*)d_in[3];
    const float* k_lstm = (const float*)d_in[4];
    const float* rk     = (const float*)d_in[5];
    const float* b_lstm = (const float*)d_in[6];
    const float* w1     = (const float*)d_in[7];
    const float* b1     = (const float*)d_in[8];
    const float* w2     = (const float*)d_in[9];
    const float* b2     = (const float*)d_in[10];
    float* out = (float*)d_out;

    // ws layout (bytes): p[1024][25][16] f32 : [0, 1638400)
    //                    emb_h (half2)       : [1638400, 4687400) -> align 4687408
    //                    convw_h (half2)     : [4687408, 4721264)
    char* ws = (char*)d_ws;
    float*        p_ws    = (float*)ws;
    unsigned int* emb_h   = (unsigned int*)(ws + 1638400);
    unsigned int* convw_h = (unsigned int*)(ws + 4687408);

    prep_kernel<<<1024, 256, 0, stream>>>(emb, conv_w, emb_h, convw_h);
    conv_embed_kernel<<<B_ / 4, 512, 0, stream>>>(tokens, emb_h, convw_h, conv_b, p_ws);
    lstm_mfma4_kernel<<<B_ / 2, 256, 0, stream>>>(p_ws, k_lstm, rk, b_lstm,
                                                  w1, b1, w2, b2, out);
}

// Round 13
// 83.553 us; speedup vs baseline: 1.5695x; 1.5695x over previous
//
#include <hip/hip_runtime.h>
#include <hip/hip_bf16.h>

#define B_  1024
#define LA  529   // token positions -> conv channels
#define EE  100   // embedding dim -> conv steps
#define NF  16    // conv filters
#define NT  50    // conv output steps
#define NS  25    // pooled steps
#define NU  100   // LSTM units
#define NJ  400   // 4*NU
#define PF  8     // e-prefetch depth

typedef float    f32x4v __attribute__((ext_vector_type(4)));
typedef short    s16x8  __attribute__((ext_vector_type(8)));
typedef _Float16 h2v    __attribute__((ext_vector_type(2)));
typedef _Float16 h16x8  __attribute__((ext_vector_type(8)));

__device__ __forceinline__ float leaky(float v) { return v >= 0.f ? v : 0.2f * v; }

__device__ __forceinline__ unsigned int pkh2(float x, float y) {
    auto p = __builtin_amdgcn_cvt_pkrtz(x, y);
    return __builtin_bit_cast(unsigned int, p);
}
__device__ __forceinline__ unsigned short f2h(float x) {
    return __builtin_bit_cast(unsigned short, (_Float16)x);
}
__device__ __forceinline__ float fdot2h(unsigned int e, unsigned int w, float acc) {
#if __has_builtin(__builtin_amdgcn_fdot2)
    return __builtin_amdgcn_fdot2(__builtin_bit_cast(h2v, e),
                                  __builtin_bit_cast(h2v, w), acc, false);
#else
    h2v ev = __builtin_bit_cast(h2v, e), wv = __builtin_bit_cast(h2v, w);
    return acc + (float)ev.x * (float)wv.x + (float)ev.y * (float)wv.y;
#endif
}

// ---------------- Kernel P: fp32 -> fp16 conversion ----------------
__global__ __launch_bounds__(256) void prep_kernel(
    const float* __restrict__ emb,      // [V*E]
    const float* __restrict__ conv_w,   // [2][529][16]
    unsigned int* __restrict__ emb_h,   // [V*E/2] packed half2
    unsigned int* __restrict__ convw_h) // [529*16] packed (w0,w1)
{
    const int gid = blockIdx.x * 256 + threadIdx.x;
    const int stride = gridDim.x * 256;
    for (int i = gid; i < (15245 * 100) / 2; i += stride) {
        const float2 v = ((const float2*)emb)[i];
        emb_h[i] = pkh2(v.x, v.y);
    }
    for (int i = gid; i < LA * NF; i += stride)
        convw_h[i] = pkh2(conv_w[i], conv_w[LA * NF + i]);
}

// ---------------- Kernel A: gather + conv + relu + maxpool ----------------
// (proven ~35us version: 1024 blocks x 256; block = batch; wave w owns
// contiguous cols; fp16 table; weights in LDS; v_dot2_f32_f16.)
__global__ __launch_bounds__(256) void conv_embed_kernel(
    const int*          __restrict__ tokens,
    const unsigned int* __restrict__ emb_h,   // [V][50] half2 rows
    const unsigned int* __restrict__ convw_h, // [529][16] (w0,w1) half2
    const float*        __restrict__ conv_b,
    float*              __restrict__ p_out)   // [B][25][16]
{
    __shared__ __align__(16) unsigned int smem[LA * NF];  // 33.9 KB (union)
    unsigned int* wlds = smem;
    float* part = (float*)smem;           // [4][50][16] after compute
    float* ylds = (float*)smem + 3200;    // [50][16]

    const int tid  = threadIdx.x;
    const int b    = blockIdx.x;
    const int lane = tid & 63;
    const int w    = __builtin_amdgcn_readfirstlane(tid >> 6);
    const int t    = lane < NT ? lane : (NT - 1);

    for (int i = tid; i < (LA * NF) / 4; i += 256)
        ((uint4*)smem)[i] = ((const uint4*)convw_h)[i];
    __syncthreads();

    const int cbase = w * 133;
    const int NC    = (w < 3) ? 133 : 130;
    const int* __restrict__ tokb = tokens + (size_t)b * LA + cbase;

    float acc[NF];
#pragma unroll
    for (int f = 0; f < NF; ++f) acc[f] = 0.f;

#define LOAD_E(dst, i_) do { \
    const int i2 = (i_); \
    const int ic = (i2 < NC) ? i2 : 0; \
    unsigned int v = emb_h[(size_t)tokb[ic] * 50 + t]; \
    if (i2 >= NC) v = 0u; \
    (dst) = v; } while (0)

    unsigned int ebuf[PF];
#pragma unroll
    for (int j = 0; j < PF; ++j) LOAD_E(ebuf[j], j);

    for (int ig = 0; ig < 136; ig += PF) {
        unsigned int enxt[PF];
#pragma unroll
        for (int j = 0; j < PF; ++j) LOAD_E(enxt[j], ig + PF + j);
#pragma unroll
        for (int j = 0; j < PF; ++j) {
            const int i  = ig + j;
            const int cc = cbase + ((i < NC) ? i : 0);
            const unsigned int* wp = wlds + cc * NF;
            unsigned int wv[NF];
#pragma unroll
            for (int q = 0; q < 4; ++q) ((uint4*)wv)[q] = ((const uint4*)wp)[q];
#pragma unroll
            for (int f = 0; f < NF; ++f) acc[f] = fdot2h(ebuf[j], wv[f], acc[f]);
        }
#pragma unroll
        for (int j = 0; j < PF; ++j) ebuf[j] = enxt[j];
    }
#undef LOAD_E

    __syncthreads();
    if (lane < NT) {
        float4* dst = (float4*)(part + (size_t)(w * NT + lane) * NF);
#pragma unroll
        for (int q = 0; q < 4; ++q) dst[q] = ((float4*)acc)[q];
    }
    __syncthreads();

    if (tid < 200) {
        const int tr = tid >> 2, fq = tid & 3;
        float4 s0 = ((float4*)(part + (0 * NT + tr) * NF))[fq];
        float4 s1 = ((float4*)(part + (1 * NT + tr) * NF))[fq];
        float4 s2 = ((float4*)(part + (2 * NT + tr) * NF))[fq];
        float4 s3 = ((float4*)(part + (3 * NT + tr) * NF))[fq];
        float4 cb = ((const float4*)conv_b)[fq];
        float4 y;
        y.x = fmaxf(s0.x + s1.x + s2.x + s3.x + cb.x, 0.f);
        y.y = fmaxf(s0.y + s1.y + s2.y + s3.y + cb.y, 0.f);
        y.z = fmaxf(s0.z + s1.z + s2.z + s3.z + cb.z, 0.f);
        y.w = fmaxf(s0.w + s1.w + s2.w + s3.w + cb.w, 0.f);
        ((float4*)(ylds + tr * NF))[fq] = y;
    }
    __syncthreads();

    for (int idx = tid; idx < NS * NF; idx += 256) {
        const int s = idx >> 4, f = idx & 15;
        p_out[(size_t)b * (NS * NF) + idx] =
            fmaxf(ylds[2 * s * NF + f], ylds[(2 * s + 1) * NF + f]);
    }
}

// ---------------- Kernel B: fp16 MFMA LSTM (r4 structure) -----------------
// 256 blocks x 512 threads, 4 batches/block (1 block/CU on all 256 CUs).
// Exactly the 44us/absmax-0 round-4 structure (z_lds round trip, 2 barriers,
// gate thread = 1 (u,b) pair, wave-7 p-prefetch) with the bf16 3-term MFMA
// replaced by fp16 single-term (proven 1.95e-3): max chain 48 -> 16 MFMA.
__global__ __launch_bounds__(512, 2) void lstm_mfma_kernel(
    const float* __restrict__ p_in,    // [B][25][16]
    const float* __restrict__ k_lstm,  // [16][400]
    const float* __restrict__ rk,      // [100][400]
    const float* __restrict__ b_lstm,  // [400]
    const float* __restrict__ w1,      // [100][64]
    const float* __restrict__ b1,      // [64]
    const float* __restrict__ w2,      // [64][3]
    const float* __restrict__ b2,      // [3]
    float*       __restrict__ out)     // [B][3]
{
    __shared__ __align__(16) unsigned short a_lds[2][4][64][8]; // dbuf, 8 KB
    __shared__ __align__(16) float z_lds[NJ][4];                // [j][b], 6.4 KB
    __shared__ float h_f32[4][NU];
    __shared__ float d_lds[4 * 64];

    const int tid  = threadIdx.x;
    const int lane = tid & 63;
    const int wid  = tid >> 6;
    const int b0   = blockIdx.x * 4;

    // zero A-buffer (pad rows b=4..15 and k=117..127 stay 0 forever)
    for (int i = tid; i < 2 * 4 * 64 * 8; i += 512) ((unsigned short*)a_lds)[i] = 0;

    // ---- stationary B-frags (fp16 single-term): wave owns tiles wid*4+i ----
    h16x8 bfr[4][4];   // [tile][chunk] = 64 VGPR
#pragma unroll
    for (int i = 0; i < 4; ++i) {
        const int ntg = wid * 4 + i;
        if (ntg < 25) {
            const int jg = ntg * 16 + (lane & 15);
#pragma unroll
            for (int c = 0; c < 4; ++c) {
                h16x8 h8;
#pragma unroll
                for (int e = 0; e < 8; ++e) {
                    const int k = c * 32 + (lane >> 4) * 8 + e;
                    float x = 0.f;
                    if (jg < NJ) {
                        if (k < NU)        x = rk[k * NJ + jg];
                        else if (k < 116)  x = k_lstm[(k - NU) * NJ + jg];
                        else if (k == 116) x = b_lstm[jg];
                    }
                    h8[e] = (_Float16)x;
                }
                bfr[i][c] = h8;
            }
        }
    }
    __syncthreads();   // a_lds zeroing complete

    // initial p (t=0): 64 slots (4 batches x 16); bias slot k=116 both buffers
    if (tid < 64) {
        const int pb = tid >> 4, pf = tid & 15;
        const float pv = p_in[(size_t)(b0 + pb) * (NS * NF) + pf];
        const int k = 100 + pf;
        a_lds[0][k >> 5][(((k >> 3) & 3) << 4) + pb][k & 7] = f2h(pv);
    }
    if (tid < 4) {
        a_lds[0][3][32 + tid][4] = 0x3C00;   // fp16 1.0
        a_lds[1][3][32 + tid][4] = 0x3C00;
    }
    float cst = 0.f;
    const int gb = tid & 3, gu = tid >> 2;   // gate thread (tid < 400)
    __syncthreads();

#pragma unroll 1
    for (int t = 0; t < NS; ++t) {
        const int cur = t & 1, nxt = cur ^ 1;
        // wave 7: prefetch p for t+1 (overlaps compute)
        float pv = 0.f;
        if (tid >= 448 && t + 1 < NS) {
            const int idx = tid - 448, pb = idx >> 4, pf = idx & 15;
            pv = p_in[(size_t)(b0 + pb) * (NS * NF) + (t + 1) * NF + pf];
        }
        if (wid * 4 < 25) {   // waves 0..6 compute
            h16x8 ah[4];
#pragma unroll
            for (int c = 0; c < 4; ++c)
                ah[c] = __builtin_bit_cast(h16x8, ((const s16x8*)a_lds[cur][c])[lane]);
#pragma unroll
            for (int i = 0; i < 4; ++i) {
                const int ntg = wid * 4 + i;
                if (ntg < 25) {
                    f32x4v z0 = {0.f, 0.f, 0.f, 0.f}, z1 = {0.f, 0.f, 0.f, 0.f};
                    z0 = __builtin_amdgcn_mfma_f32_16x16x32_f16(ah[0], bfr[i][0], z0, 0, 0, 0);
                    z1 = __builtin_amdgcn_mfma_f32_16x16x32_f16(ah[1], bfr[i][1], z1, 0, 0, 0);
                    z0 = __builtin_amdgcn_mfma_f32_16x16x32_f16(ah[2], bfr[i][2], z0, 0, 0, 0);
                    z1 = __builtin_amdgcn_mfma_f32_16x16x32_f16(ah[3], bfr[i][3], z1, 0, 0, 0);
                    const f32x4v acc = z0 + z1;
                    if (lane < 16) {   // rows 0..3 = real batches
                        *((f32x4v*)z_lds[ntg * 16 + lane]) = acc;
                    }
                }
            }
        }
        __syncthreads();
        // gates: thread -> (b = tid&3, u = tid>>2)
        if (tid < 4 * NU) {
            const float zi = z_lds[gu][gb];
            const float zf = z_lds[gu + 100][gb];
            const float zg = z_lds[gu + 200][gb];
            const float zo = z_lds[gu + 300][gb];
            const float ig  = 1.f / (1.f + __expf(-zi));
            const float fg_ = 1.f / (1.f + __expf(-zf));
            const float og  = 1.f / (1.f + __expf(-zo));
            cst = fg_ * cst + ig * leaky(zg);
            const float h = og * leaky(cst);
            h_f32[gb][gu] = h;
            const int c = gu >> 5, ls = (((gu >> 3) & 3) << 4) + gb, e = gu & 7;
            a_lds[nxt][c][ls][e] = f2h(h);
        }
        if (tid >= 448 && t + 1 < NS) {   // write p slots for t+1
            const int idx = tid - 448, pb = idx >> 4, pf = idx & 15;
            const int k = 100 + pf;
            a_lds[nxt][k >> 5][(((k >> 3) & 3) << 4) + pb][k & 7] = f2h(pv);
        }
        __syncthreads();
    }

    // dense head: d = tanh(h @ w1 + b1)
    if (tid < 256) {
        const int hb = tid >> 6, m = tid & 63;
        float a = b1[m];
#pragma unroll 4
        for (int u = 0; u < NU; ++u) a += h_f32[hb][u] * w1[u * 64 + m];
        d_lds[hb * 64 + m] = tanhf(a);
    }
    __syncthreads();

    // logits + softmax (3 classes)
    if (tid < 4) {
        float l0 = b2[0], l1 = b2[1], l2 = b2[2];
        for (int m = 0; m < 64; ++m) {
            const float d = d_lds[tid * 64 + m];
            l0 += d * w2[m * 3 + 0];
            l1 += d * w2[m * 3 + 1];
            l2 += d * w2[m * 3 + 2];
        }
        const float mx = fmaxf(l0, fmaxf(l1, l2));
        const float e0 = __expf(l0 - mx), e1 = __expf(l1 - mx), e2 = __expf(l2 - mx);
        const float inv = 1.f / (e0 + e1 + e2);
        out[(b0 + tid) * 3 + 0] = e0 * inv;
        out[(b0 + tid) * 3 + 1] = e1 * inv;
        out[(b0 + tid) * 3 + 2] = e2 * inv;
    }
}

extern "C" void kernel_launch(void* const* d_in, const int* in_sizes, int n_in,
                              void* d_out, int out_size, void* d_ws, size_t ws_size,
                              hipStream_t stream) {
    const int*   tokens = (const int*)  d_in[0];
    const float* emb    = (const float*)d_in[1];
    const float* conv_w = (const float*)d_in[2];
    const float* conv_b = (const float*)d_in[3];
    const float* k_lstm = (const float*)d_in[4];
    const float* rk     = (const float*)d_in[5];
    const float* b_lstm = (const float*)d_in[6];
    const float* w1     = (const float*)d_in[7];
    const float* b1     = (const float*)d_in[8];
    const float* w2     = (const float*)d_in[9];
    const float* b2     = (const float*)d_in[10];
    float* out = (float*)d_out;

    // ws layout (bytes): p[1024][25][16] f32 : [0, 1638400)
    //                    emb_h (half2)       : [1638400, 4687400) -> align 4687408
    //                    convw_h (half2)     : [4687408, 4721264)
    char* ws = (char*)d_ws;
    float*        p_ws    = (float*)ws;
    unsigned int* emb_h   = (unsigned int*)(ws + 1638400);
    unsigned int* convw_h = (unsigned int*)(ws + 4687408);

    prep_kernel<<<1024, 256, 0, stream>>>(emb, conv_w, emb_h, convw_h);
    conv_embed_kernel<<<B_, 256, 0, stream>>>(tokens, emb_h, convw_h, conv_b, p_ws);
    lstm_mfma_kernel<<<B_ / 4, 512, 0, stream>>>(p_ws, k_lstm, rk, b_lstm,
                                                 w1, b1, w2, b2, out);
}